// Round 10
// baseline (597.159 us; speedup 1.0000x reference)
//
#include <hip/hip_runtime.h>
#include <hip/hip_bf16.h>

#define N_NODES 100000
#define N_EDGES 3200000
#define BSH 8                         // 256 nodes per bucket
#define NB 391                        // ceil(N_NODES / 256)

typedef __hip_bfloat16 bf16;

// readlane broadcast: float from lane k (k compile-time constant)
#define RL(v, k) __int_as_float(__builtin_amdgcn_readlane(__float_as_int(v), (k)))

// ---- dtype-flexible load: flag==1 -> f32, flag==0 -> bf16 ----
__device__ __forceinline__ float loadF(const void* p, long long i, int isf32) {
    if (isf32) return ((const float*)p)[i];
    unsigned short v = ((const unsigned short*)p)[i];
    union { unsigned u; float f; } c;
    c.u = ((unsigned)v) << 16;
    return c.f;
}

// ---- packed edge: src (17 bits) << 15 | bf16-weight-bits (15 bits; w in [0,1)) ----
__device__ __forceinline__ unsigned packEdge(int s, float w) {
    bf16 b = __float2bfloat16(w);
    unsigned short bits = *(unsigned short*)&b;
    return ((unsigned)s << 15) | (unsigned)(bits & 0x7FFF);
}
__device__ __forceinline__ int edgeSrc(unsigned u) { return (int)(u >> 15); }
__device__ __forceinline__ float edgeW(unsigned u) {
    union { unsigned x; float f; } c;
    c.x = (u & 0x7FFFu) << 16;
    return c.f;
}

// ---- weight canonical layout (float offsets inside wts) ----
#define W_GAMMA 0
#define W_BETA 8
#define W_C1PW 16
#define W_C1PB 48
#define W_C1LW 56
#define W_C1LB 376
#define W_C1RW 440
#define W_C2PW 760
#define W_C2PB 4856
#define W_C2LW 4920
#define W_C2LB 9016
#define W_C2RW 9080
#define W_C3PW 13176
#define W_C3PB 17272
#define W_C3LW 17336
#define W_C3LB 17656
#define W_C3RW 17664

// ---------------- dtype detection ----------------
__global__ void detect_dtype(const void* ew, int* flag) {
    const unsigned short* u = (const unsigned short*)ew;
    int lane = threadIdx.x;
    int big = 0;
    for (int i = lane; i < 1024; i += 64) {
        unsigned short v = u[2 * i];
        int ex = (v >> 7) & 0xFF;
        if (ex >= 128) big++;
    }
#pragma unroll
    for (int o = 32; o; o >>= 1) big += __shfl_xor(big, o, 64);
    if (lane == 0) *flag = (big > 100) ? 1 : 0;
}

// ---------------- convert all weight tensors to canonical fp32 ----------------
__global__ void cvt_weights(const int* flag,
                            const void* p0, const void* p1, const void* p2, const void* p3,
                            const void* p4, const void* p5, const void* p6, const void* p7,
                            const void* p8, const void* p9, const void* p10, const void* p11,
                            const void* p12, const void* p13, const void* p14, const void* p15,
                            const void* p16, float* __restrict__ wts) {
    const void* ptrs[17] = {p0, p1, p2, p3, p4, p5, p6, p7, p8,
                            p9, p10, p11, p12, p13, p14, p15, p16};
    const int sz[17] = {5, 5, 25, 5, 320, 64, 320, 4096, 64,
                        4096, 64, 4096, 4096, 64, 320, 5, 320};
    const int off[17] = {W_GAMMA, W_BETA, W_C1PW, W_C1PB, W_C1LW, W_C1LB, W_C1RW,
                         W_C2PW, W_C2PB, W_C2LW, W_C2LB, W_C2RW,
                         W_C3PW, W_C3PB, W_C3LW, W_C3LB, W_C3RW};
    int t = blockIdx.x;
    int isf32 = *flag;
    for (int i = threadIdx.x; i < sz[t]; i += blockDim.x)
        wts[off[t] + i] = loadF(ptrs[t], i, isf32);
}

// ---------------- BN statistics ----------------
__global__ void bn_stats(const void* __restrict__ h, const int* __restrict__ flag,
                         float* __restrict__ stats) {
    int isf32 = *flag;
    float s[5] = {0, 0, 0, 0, 0}, q[5] = {0, 0, 0, 0, 0};
    int tid = blockIdx.x * blockDim.x + threadIdx.x;
    int stride = gridDim.x * blockDim.x;
    for (int i = tid; i < N_NODES; i += stride) {
#pragma unroll
        for (int f = 0; f < 5; f++) {
            float v = loadF(h, i * 5 + f, isf32);
            s[f] += v;
            q[f] += v * v;
        }
    }
#pragma unroll
    for (int f = 0; f < 5; f++) {
#pragma unroll
        for (int o = 32; o; o >>= 1) {
            s[f] += __shfl_xor(s[f], o, 64);
            q[f] += __shfl_xor(q[f], o, 64);
        }
    }
    __shared__ float ls[4][10];
    int wave = threadIdx.x >> 6, lane = threadIdx.x & 63;
    if (lane == 0) {
#pragma unroll
        for (int f = 0; f < 5; f++) { ls[wave][f] = s[f]; ls[wave][5 + f] = q[f]; }
    }
    __syncthreads();
    if (threadIdx.x < 10) {
        float v = ls[0][threadIdx.x] + ls[1][threadIdx.x] + ls[2][threadIdx.x] + ls[3][threadIdx.x];
        int idx = (threadIdx.x < 5) ? threadIdx.x : (threadIdx.x - 5 + 8);
        atomicAdd(&stats[idx], v);
    }
}

// ---------------- BN finalize + apply + conv1 projection (5->5), fused; xp1 padded to 8 ----
__global__ void bn_proj1(const void* __restrict__ h, const int* __restrict__ flag,
                         const float* __restrict__ stats, const float* __restrict__ wts,
                         float* __restrict__ xbn, float* __restrict__ xp1) {
    __shared__ float s_sc[5], s_sb[5];
    if (threadIdx.x < 5) {
        int f = threadIdx.x;
        float mean = stats[f] / (float)N_NODES;
        float var = stats[8 + f] / (float)N_NODES - mean * mean;
        float sc = wts[W_GAMMA + f] * rsqrtf(var + 1e-5f);
        s_sc[f] = sc;
        s_sb[f] = wts[W_BETA + f] - mean * sc;
    }
    __syncthreads();
    int isf32 = *flag;
    int i = blockIdx.x * blockDim.x + threadIdx.x;
    if (i >= N_NODES) return;
    float x[5];
#pragma unroll
    for (int f = 0; f < 5; f++)
        x[f] = loadF(h, i * 5 + f, isf32) * s_sc[f] + s_sb[f];
#pragma unroll
    for (int f = 0; f < 5; f++) xbn[i * 5 + f] = x[f];
#pragma unroll
    for (int j = 0; j < 5; j++) {
        float a = wts[W_C1PB + j];
#pragma unroll
        for (int k = 0; k < 5; k++) a += x[k] * wts[W_C1PW + k * 5 + j];
        xp1[i * 8 + j] = fmaxf(a, 0.f);
    }
}

// ---------------- CSR build, phase A1: bucket histogram ----------------
__global__ void __launch_bounds__(256) bucket_hist(const int* __restrict__ dst,
                                                   int* __restrict__ bucketCnt) {
    __shared__ int hcnt[NB];
    for (int i = threadIdx.x; i < NB; i += 256) hcnt[i] = 0;
    __syncthreads();
    int per = (N_EDGES + gridDim.x - 1) / gridDim.x;
    int s = blockIdx.x * per;
    int e = min(s + per, N_EDGES);
    for (int i = s + threadIdx.x; i < e; i += 256)
        atomicAdd(&hcnt[dst[i] >> BSH], 1);
    __syncthreads();
    for (int i = threadIdx.x; i < NB; i += 256)
        if (hcnt[i]) atomicAdd(&bucketCnt[i], hcnt[i]);
}

// ---------------- phase A2: exclusive scan of 391 bucket counts ----------------
__global__ void __launch_bounds__(512) bucket_scan(const int* __restrict__ bucketCnt,
                                                   int* __restrict__ bucketStart,
                                                   int* __restrict__ bucketCursor) {
    int tid = threadIdx.x, lane = tid & 63, w = tid >> 6;
    int v = (tid < NB) ? bucketCnt[tid] : 0;
    int sc = v;
#pragma unroll
    for (int o = 1; o < 64; o <<= 1) {
        int t = __shfl_up(sc, o, 64);
        if (lane >= o) sc += t;
    }
    __shared__ int ws[8];
    if (lane == 63) ws[w] = sc;
    __syncthreads();
    if (w == 0) {
        int wv = (lane < 8) ? ws[lane] : 0;
        int s2 = wv;
#pragma unroll
        for (int o = 1; o < 8; o <<= 1) {
            int t = __shfl_up(s2, o, 64);
            if (lane >= o) s2 += t;
        }
        if (lane < 8) ws[lane] = s2;
    }
    __syncthreads();
    int woff = w ? ws[w - 1] : 0;
    int ex = woff + sc - v;
    if (tid < NB) {
        bucketStart[tid] = ex;
        bucketCursor[tid] = ex;
    }
    if (tid == 0) bucketStart[NB] = N_EDGES;
}

// ---------------- phase A3: stage edges bucket-contiguously ({dst, packed}) ----------
__global__ void __launch_bounds__(256) bucket_stage(const int* __restrict__ src,
                                                    const int* __restrict__ dst,
                                                    const void* __restrict__ ew,
                                                    const int* __restrict__ flag,
                                                    int* __restrict__ bucketCursor,
                                                    uint2* __restrict__ stage) {
    __shared__ int hcnt[NB], cur[NB];
    int isf32 = *flag;
    for (int i = threadIdx.x; i < NB; i += 256) hcnt[i] = 0;
    __syncthreads();
    int per = (N_EDGES + gridDim.x - 1) / gridDim.x;
    int s = blockIdx.x * per;
    int e = min(s + per, N_EDGES);
    for (int i = s + threadIdx.x; i < e; i += 256)
        atomicAdd(&hcnt[dst[i] >> BSH], 1);
    __syncthreads();
    for (int i = threadIdx.x; i < NB; i += 256)
        cur[i] = hcnt[i] ? atomicAdd(&bucketCursor[i], hcnt[i]) : 0;
    __syncthreads();
    for (int i = s + threadIdx.x; i < e; i += 256) {
        int d = dst[i];
        int slot = atomicAdd(&cur[d >> BSH], 1);
        stage[slot] = make_uint2((unsigned)d, packEdge(src[i], loadF(ew, i, isf32)));
    }
}

// ---------------- phase B: per-bucket -> node-level CSR (start + perm) ----------------
__global__ void __launch_bounds__(256) bucket_place(const uint2* __restrict__ stage,
                                                    const int* __restrict__ bucketStart,
                                                    int* __restrict__ start,
                                                    unsigned* __restrict__ perm) {
    int b = blockIdx.x, tid = threadIdx.x;
    int base = bucketStart[b];
    int cnt = bucketStart[b + 1] - base;
    int n0 = b << BSH;
    int nn = min(256, N_NODES - n0);
    __shared__ int lcnt[256], loff[256], ws[4];
    lcnt[tid] = 0;
    __syncthreads();
    for (int i = tid; i < cnt; i += 256)
        atomicAdd(&lcnt[stage[base + i].x & 255], 1);
    __syncthreads();
    int lane = tid & 63, w = tid >> 6;
    int v = lcnt[tid];
    int sc = v;
#pragma unroll
    for (int o = 1; o < 64; o <<= 1) {
        int t = __shfl_up(sc, o, 64);
        if (lane >= o) sc += t;
    }
    if (lane == 63) ws[w] = sc;
    __syncthreads();
    int woff = 0;
    for (int k = 0; k < w; k++) woff += ws[k];
    loff[tid] = woff + sc - v;
    __syncthreads();
    if (tid < nn) start[n0 + tid] = base + loff[tid];
    if (b == 0 && tid == 0) start[N_NODES] = N_EDGES;
    lcnt[tid] = 0;
    __syncthreads();
    for (int i = tid; i < cnt; i += 256) {
        uint2 sv = stage[base + i];
        int l = sv.x & 255;
        int p = atomicAdd(&lcnt[l], 1);
        perm[base + loff[l] + p] = sv.y;
    }
}

// ---------------- conv1: lane-parallel gather (padded rows) + epilogue + conv2 proj ----
__global__ void __launch_bounds__(256) conv1_fused(const float* __restrict__ xp1,
                                                   const float* __restrict__ xbn,
                                                   const int* __restrict__ start,
                                                   const unsigned* __restrict__ perm,
                                                   const float* __restrict__ wts,
                                                   float* __restrict__ x1,
                                                   bf16* __restrict__ y2) {
    int lane = threadIdx.x & 63;
    int wid = __builtin_amdgcn_readfirstlane((blockIdx.x * blockDim.x + threadIdx.x) >> 6);
    int nw = (gridDim.x * blockDim.x) >> 6;
    float Wlw[5], Wrw[5];
#pragma unroll
    for (int k = 0; k < 5; k++) {
        Wlw[k] = wts[W_C1LW + k * 64 + lane];
        Wrw[k] = wts[W_C1RW + k * 64 + lane];
    }
    float lb = wts[W_C1LB + lane];
    float W1[64], W2[64];
#pragma unroll
    for (int k = 0; k < 64; k++) W1[k] = wts[W_C2PW + k * 64 + lane];
#pragma unroll
    for (int k = 0; k < 64; k++) W2[k] = wts[W_C2LW + k * 64 + lane];
    float pb = wts[W_C2PB + lane];
    for (int node = wid; node < N_NODES; node += nw) {
        int e0 = start[node], e1 = start[node + 1];
        float s0 = 0, s1 = 0, s2 = 0, s3 = 0, s4 = 0;
        for (int eb = e0; eb < e1; eb += 64) {
            int e = eb + lane;
            if (e < e1) {
                unsigned p = perm[e];
                float w = edgeW(p);
                const float* row = xp1 + (size_t)edgeSrc(p) * 8;
                float4 v4 = *(const float4*)row;
                float v5 = row[4];
                s0 += v4.x * w; s1 += v4.y * w; s2 += v4.z * w;
                s3 += v4.w * w; s4 += v5 * w;
            }
        }
#pragma unroll
        for (int o = 32; o; o >>= 1) {
            s0 += __shfl_xor(s0, o, 64);
            s1 += __shfl_xor(s1, o, 64);
            s2 += __shfl_xor(s2, o, 64);
            s3 += __shfl_xor(s3, o, 64);
            s4 += __shfl_xor(s4, o, 64);
        }
        float ic = 1.f / fmaxf((float)(e1 - e0), 1.f);
        float xb = (lane < 5) ? xbn[node * 5 + lane] : 0.f;
        float out = lb + s0 * ic * Wlw[0] + s1 * ic * Wlw[1] + s2 * ic * Wlw[2] +
                    s3 * ic * Wlw[3] + s4 * ic * Wlw[4];
#pragma unroll
        for (int k = 0; k < 5; k++) out += RL(xb, k) * Wrw[k];
        float ss = out * out;
#pragma unroll
        for (int o = 32; o; o >>= 1) ss += __shfl_xor(ss, o, 64);
        float xv = fmaxf(out / fmaxf(sqrtf(ss), 1e-12f), 0.f);
        x1[(size_t)node * 64 + lane] = xv;
        float a0 = pb, a1 = 0.f, a2 = 0.f, a3 = 0.f;
#pragma unroll
        for (int k = 0; k < 64; k += 4) {
            a0 += RL(xv, k) * W1[k];
            a1 += RL(xv, k + 1) * W1[k + 1];
            a2 += RL(xv, k + 2) * W1[k + 2];
            a3 += RL(xv, k + 3) * W1[k + 3];
        }
        float xp = fmaxf((a0 + a1) + (a2 + a3), 0.f);
        float b0 = 0.f, b1 = 0.f, b2 = 0.f, b3 = 0.f;
#pragma unroll
        for (int k = 0; k < 64; k += 4) {
            b0 += RL(xp, k) * W2[k];
            b1 += RL(xp, k + 1) * W2[k + 1];
            b2 += RL(xp, k + 2) * W2[k + 2];
            b3 += RL(xp, k + 3) * W2[k + 3];
        }
        y2[(size_t)node * 64 + lane] = __float2bfloat16((b0 + b1) + (b2 + b3));
    }
}

// ---------------- conv2 + conv3-projection: gather + root + L2norm + proj3 -> y3 -------
__global__ void __launch_bounds__(256) conv2_fused3(const bf16* __restrict__ y2,
                                                    const int* __restrict__ start,
                                                    const unsigned* __restrict__ perm,
                                                    const float* __restrict__ x1,
                                                    const float* __restrict__ wts,
                                                    float* __restrict__ x2,
                                                    float* __restrict__ y3) {
    int lane = threadIdx.x & 63;
    int wid = __builtin_amdgcn_readfirstlane((blockIdx.x * blockDim.x + threadIdx.x) >> 6);
    int nw = (gridDim.x * blockDim.x) >> 6;
    float W[64];
#pragma unroll
    for (int k = 0; k < 64; k++) W[k] = wts[W_C2RW + k * 64 + lane];
    float lb = wts[W_C2LB + lane];
    float W3[64], Wl3[5];
#pragma unroll
    for (int k = 0; k < 64; k++) W3[k] = wts[W_C3PW + k * 64 + lane];
#pragma unroll
    for (int j = 0; j < 5; j++) Wl3[j] = wts[W_C3LW + lane * 5 + j];
    float pb3 = wts[W_C3PB + lane];
    for (int node = wid; node < N_NODES; node += nw) {
        int e0 = start[node], e1 = start[node + 1];
        float acc = 0.f;
        int e = e0;
        for (; e + 16 <= e1; e += 16) {
            unsigned p[16];
#pragma unroll
            for (int u = 0; u < 16; u++) p[u] = perm[e + u];
            float v[16];
#pragma unroll
            for (int u = 0; u < 16; u++)
                v[u] = __bfloat162float(y2[(size_t)edgeSrc(p[u]) * 64 + lane]);
#pragma unroll
            for (int u = 0; u < 16; u++) acc += v[u] * edgeW(p[u]);
        }
        for (; e + 4 <= e1; e += 4) {
            unsigned p[4];
#pragma unroll
            for (int u = 0; u < 4; u++) p[u] = perm[e + u];
            float v[4];
#pragma unroll
            for (int u = 0; u < 4; u++)
                v[u] = __bfloat162float(y2[(size_t)edgeSrc(p[u]) * 64 + lane]);
#pragma unroll
            for (int u = 0; u < 4; u++) acc += v[u] * edgeW(p[u]);
        }
        for (; e < e1; e++) {
            unsigned p = perm[e];
            acc += __bfloat162float(y2[(size_t)edgeSrc(p) * 64 + lane]) * edgeW(p);
        }
        float ic = 1.f / fmaxf((float)(e1 - e0), 1.f);
        float xv = x1[(size_t)node * 64 + lane];
        float o0 = acc * ic + lb, o1 = 0.f, o2 = 0.f, o3 = 0.f;
#pragma unroll
        for (int k = 0; k < 64; k += 4) {
            o0 += RL(xv, k) * W[k];
            o1 += RL(xv, k + 1) * W[k + 1];
            o2 += RL(xv, k + 2) * W[k + 2];
            o3 += RL(xv, k + 3) * W[k + 3];
        }
        float out = (o0 + o1) + (o2 + o3);
        float ss = out * out;
#pragma unroll
        for (int o = 32; o; o >>= 1) ss += __shfl_xor(ss, o, 64);
        float x2v = fmaxf(out / fmaxf(sqrtf(ss), 1e-12f), 0.f);
        x2[(size_t)node * 64 + lane] = x2v;
        // conv3 projection: xp = relu(x2 @ pw3 + pb3); y3 = xp @ lw3 (64 -> 5, padded 8)
        float a0 = pb3, a1 = 0.f, a2 = 0.f, a3 = 0.f;
#pragma unroll
        for (int k = 0; k < 64; k += 4) {
            a0 += RL(x2v, k) * W3[k];
            a1 += RL(x2v, k + 1) * W3[k + 1];
            a2 += RL(x2v, k + 2) * W3[k + 2];
            a3 += RL(x2v, k + 3) * W3[k + 3];
        }
        float xp = fmaxf((a0 + a1) + (a2 + a3), 0.f);
#pragma unroll
        for (int j = 0; j < 5; j++) {
            float p = xp * Wl3[j];
#pragma unroll
            for (int o = 32; o; o >>= 1) p += __shfl_xor(p, o, 64);
            if (lane == j) y3[(size_t)node * 8 + j] = p;
        }
    }
}

// ---------------- conv3: lane-parallel gather (padded rows) + epilogue (no relu) -------
__global__ void __launch_bounds__(256) conv3_fused(const float* __restrict__ y3,
                                                   const float* __restrict__ x2,
                                                   const int* __restrict__ start,
                                                   const unsigned* __restrict__ perm,
                                                   const float* __restrict__ wts,
                                                   const int* __restrict__ flag,
                                                   void* __restrict__ outp) {
    int lane = threadIdx.x & 63;
    int wid = __builtin_amdgcn_readfirstlane((blockIdx.x * blockDim.x + threadIdx.x) >> 6);
    int nw = (gridDim.x * blockDim.x) >> 6;
    float Wr[5];
#pragma unroll
    for (int j = 0; j < 5; j++) Wr[j] = wts[W_C3RW + lane * 5 + j];
    float lb3[5];
#pragma unroll
    for (int j = 0; j < 5; j++) lb3[j] = wts[W_C3LB + j];
    int isf32 = *flag;
    for (int node = wid; node < N_NODES; node += nw) {
        int e0 = start[node], e1 = start[node + 1];
        float s0 = 0, s1 = 0, s2 = 0, s3 = 0, s4 = 0;
        for (int eb = e0; eb < e1; eb += 64) {
            int e = eb + lane;
            if (e < e1) {
                unsigned p = perm[e];
                float w = edgeW(p);
                const float* row = y3 + (size_t)edgeSrc(p) * 8;
                float4 v4 = *(const float4*)row;
                float v5 = row[4];
                s0 += v4.x * w; s1 += v4.y * w; s2 += v4.z * w;
                s3 += v4.w * w; s4 += v5 * w;
            }
        }
#pragma unroll
        for (int o = 32; o; o >>= 1) {
            s0 += __shfl_xor(s0, o, 64);
            s1 += __shfl_xor(s1, o, 64);
            s2 += __shfl_xor(s2, o, 64);
            s3 += __shfl_xor(s3, o, 64);
            s4 += __shfl_xor(s4, o, 64);
        }
        float ic = 1.f / fmaxf((float)(e1 - e0), 1.f);
        float xv = x2[(size_t)node * 64 + lane];
        float m[5] = {s0 * ic, s1 * ic, s2 * ic, s3 * ic, s4 * ic};
        float r[5], ss = 0.f;
#pragma unroll
        for (int j = 0; j < 5; j++) {
            float p = xv * Wr[j];
#pragma unroll
            for (int o = 32; o; o >>= 1) p += __shfl_xor(p, o, 64);
            r[j] = p + m[j] + lb3[j];
            ss += r[j] * r[j];
        }
        float inv = 1.f / fmaxf(sqrtf(ss), 1e-12f);
#pragma unroll
        for (int j = 0; j < 5; j++) {
            if (lane == j) {
                float v = r[j] * inv;
                if (isf32) ((float*)outp)[node * 5 + j] = v;
                else ((bf16*)outp)[node * 5 + j] = __float2bfloat16(v);
            }
        }
    }
}

extern "C" void kernel_launch(void* const* d_in, const int* in_sizes, int n_in,
                              void* d_out, int out_size, void* d_ws, size_t ws_size,
                              hipStream_t stream) {
    const void* h = d_in[0];
    const int* ei = (const int*)d_in[1];
    const int* src = ei;
    const int* dst = ei + N_EDGES;
    const void* ew = d_in[2];

    float* W = (float*)d_ws;
    int* flag = (int*)W;                            // [0]
    float* stats = W + 16;                          // 32 floats
    float* wts = W + 64;                            // ~18k floats
    float* xbn = W + 20480;                         // N*5
    float* xp1 = xbn + N_NODES * 5;                 // N*8 padded (aliased by y3 later)
    int* startp = (int*)(xp1 + N_NODES * 8);        // N+1 ints (+pad)
    int* bucketCnt = startp + N_NODES + 64;         // NB ints
    int* bucketStart = bucketCnt + NB + 1;          // NB+1 ints
    int* bucketCursor = bucketStart + NB + 1;       // NB ints
    unsigned* perm = (unsigned*)(bucketCursor + NB + 62); // E u32 (packed src|w)
    float* x1 = (float*)(perm + N_EDGES);           // N*64 f32
    uint2* stage = (uint2*)x1;                      // E uint2 (dead before x1 written)
    bf16* y2 = (bf16*)(x1 + (size_t)N_NODES * 64);  // N*64 bf16
    float* x2 = x1;                                 // alias: per-thread same-idx read->write
    float* y3 = xp1;                                // alias: xp1 dead after conv1_fused

    detect_dtype<<<1, 64, 0, stream>>>(ew, flag);
    cvt_weights<<<17, 256, 0, stream>>>(flag,
        d_in[3], d_in[4],
        d_in[5], d_in[6], d_in[7], d_in[8], d_in[9],
        d_in[10], d_in[11], d_in[12], d_in[13], d_in[14],
        d_in[15], d_in[16], d_in[17], d_in[18], d_in[19],
        wts);

    hipMemsetAsync(stats, 0, 32 * sizeof(float), stream);
    hipMemsetAsync(bucketCnt, 0, NB * sizeof(int), stream);

    bn_stats<<<200, 256, 0, stream>>>(h, flag, stats);
    bn_proj1<<<(N_NODES + 255) / 256, 256, 0, stream>>>(h, flag, stats, wts, xbn, xp1);

    // CSR build: bucketed two-phase (no global random-write-through)
    bucket_hist<<<512, 256, 0, stream>>>(dst, bucketCnt);
    bucket_scan<<<1, 512, 0, stream>>>(bucketCnt, bucketStart, bucketCursor);
    bucket_stage<<<512, 256, 0, stream>>>(src, dst, ew, flag, bucketCursor, stage);
    bucket_place<<<NB, 256, 0, stream>>>(stage, bucketStart, startp, perm);

    // conv1: gather + epilogue + conv2-projection
    conv1_fused<<<2048, 256, 0, stream>>>(xp1, xbn, startp, perm, wts, x1, y2);

    // conv2 (+ conv3 projection fused)
    conv2_fused3<<<4096, 256, 0, stream>>>(y2, startp, perm, x1, wts, x2, y3);

    // conv3: gather + epilogue
    conv3_fused<<<2048, 256, 0, stream>>>(y3, x2, startp, perm, wts, flag, d_out);
}

// Round 11
// 566.885 us; speedup vs baseline: 1.0534x; 1.0534x over previous
//
#include <hip/hip_runtime.h>
#include <hip/hip_bf16.h>

#define N_NODES 100000
#define N_EDGES 3200000
#define BSH 8                         // 256 nodes per bucket
#define NB 391                        // ceil(N_NODES / 256)

typedef __hip_bfloat16 bf16;

// readlane broadcast: float from lane k (k compile-time constant)
#define RL(v, k) __int_as_float(__builtin_amdgcn_readlane(__float_as_int(v), (k)))

// ---- dtype-flexible load: flag==1 -> f32, flag==0 -> bf16 ----
__device__ __forceinline__ float loadF(const void* p, long long i, int isf32) {
    if (isf32) return ((const float*)p)[i];
    unsigned short v = ((const unsigned short*)p)[i];
    union { unsigned u; float f; } c;
    c.u = ((unsigned)v) << 16;
    return c.f;
}

// ---- packed edge: src (17 bits) << 15 | bf16-weight-bits (15 bits; w in [0,1)) ----
__device__ __forceinline__ unsigned packEdge(int s, float w) {
    bf16 b = __float2bfloat16(w);
    unsigned short bits = *(unsigned short*)&b;
    return ((unsigned)s << 15) | (unsigned)(bits & 0x7FFF);
}
__device__ __forceinline__ int edgeSrc(unsigned u) { return (int)(u >> 15); }
__device__ __forceinline__ float edgeW(unsigned u) {
    union { unsigned x; float f; } c;
    c.x = (u & 0x7FFFu) << 16;
    return c.f;
}

// ---- weight canonical layout (float offsets inside wts) ----
#define W_GAMMA 0
#define W_BETA 8
#define W_C1PW 16
#define W_C1PB 48
#define W_C1LW 56
#define W_C1LB 376
#define W_C1RW 440
#define W_C2PW 760
#define W_C2PB 4856
#define W_C2LW 4920
#define W_C2LB 9016
#define W_C2RW 9080
#define W_C3PW 13176
#define W_C3PB 17272
#define W_C3LW 17336
#define W_C3LB 17656
#define W_C3RW 17664

// ---------------- dtype detection ----------------
__global__ void detect_dtype(const void* ew, int* flag) {
    const unsigned short* u = (const unsigned short*)ew;
    int lane = threadIdx.x;
    int big = 0;
    for (int i = lane; i < 1024; i += 64) {
        unsigned short v = u[2 * i];
        int ex = (v >> 7) & 0xFF;
        if (ex >= 128) big++;
    }
#pragma unroll
    for (int o = 32; o; o >>= 1) big += __shfl_xor(big, o, 64);
    if (lane == 0) *flag = (big > 100) ? 1 : 0;
}

// ---------------- convert all weight tensors to canonical fp32 ----------------
__global__ void cvt_weights(const int* flag,
                            const void* p0, const void* p1, const void* p2, const void* p3,
                            const void* p4, const void* p5, const void* p6, const void* p7,
                            const void* p8, const void* p9, const void* p10, const void* p11,
                            const void* p12, const void* p13, const void* p14, const void* p15,
                            const void* p16, float* __restrict__ wts) {
    const void* ptrs[17] = {p0, p1, p2, p3, p4, p5, p6, p7, p8,
                            p9, p10, p11, p12, p13, p14, p15, p16};
    const int sz[17] = {5, 5, 25, 5, 320, 64, 320, 4096, 64,
                        4096, 64, 4096, 4096, 64, 320, 5, 320};
    const int off[17] = {W_GAMMA, W_BETA, W_C1PW, W_C1PB, W_C1LW, W_C1LB, W_C1RW,
                         W_C2PW, W_C2PB, W_C2LW, W_C2LB, W_C2RW,
                         W_C3PW, W_C3PB, W_C3LW, W_C3LB, W_C3RW};
    int t = blockIdx.x;
    int isf32 = *flag;
    for (int i = threadIdx.x; i < sz[t]; i += blockDim.x)
        wts[off[t] + i] = loadF(ptrs[t], i, isf32);
}

// ---------------- BN statistics ----------------
__global__ void bn_stats(const void* __restrict__ h, const int* __restrict__ flag,
                         float* __restrict__ stats) {
    int isf32 = *flag;
    float s[5] = {0, 0, 0, 0, 0}, q[5] = {0, 0, 0, 0, 0};
    int tid = blockIdx.x * blockDim.x + threadIdx.x;
    int stride = gridDim.x * blockDim.x;
    for (int i = tid; i < N_NODES; i += stride) {
#pragma unroll
        for (int f = 0; f < 5; f++) {
            float v = loadF(h, i * 5 + f, isf32);
            s[f] += v;
            q[f] += v * v;
        }
    }
#pragma unroll
    for (int f = 0; f < 5; f++) {
#pragma unroll
        for (int o = 32; o; o >>= 1) {
            s[f] += __shfl_xor(s[f], o, 64);
            q[f] += __shfl_xor(q[f], o, 64);
        }
    }
    __shared__ float ls[4][10];
    int wave = threadIdx.x >> 6, lane = threadIdx.x & 63;
    if (lane == 0) {
#pragma unroll
        for (int f = 0; f < 5; f++) { ls[wave][f] = s[f]; ls[wave][5 + f] = q[f]; }
    }
    __syncthreads();
    if (threadIdx.x < 10) {
        float v = ls[0][threadIdx.x] + ls[1][threadIdx.x] + ls[2][threadIdx.x] + ls[3][threadIdx.x];
        int idx = (threadIdx.x < 5) ? threadIdx.x : (threadIdx.x - 5 + 8);
        atomicAdd(&stats[idx], v);
    }
}

// ---------------- BN finalize + apply + conv1 projection (5->5), fused; xp1 padded to 8 ----
__global__ void bn_proj1(const void* __restrict__ h, const int* __restrict__ flag,
                         const float* __restrict__ stats, const float* __restrict__ wts,
                         float* __restrict__ xbn, float* __restrict__ xp1) {
    __shared__ float s_sc[5], s_sb[5];
    if (threadIdx.x < 5) {
        int f = threadIdx.x;
        float mean = stats[f] / (float)N_NODES;
        float var = stats[8 + f] / (float)N_NODES - mean * mean;
        float sc = wts[W_GAMMA + f] * rsqrtf(var + 1e-5f);
        s_sc[f] = sc;
        s_sb[f] = wts[W_BETA + f] - mean * sc;
    }
    __syncthreads();
    int isf32 = *flag;
    int i = blockIdx.x * blockDim.x + threadIdx.x;
    if (i >= N_NODES) return;
    float x[5];
#pragma unroll
    for (int f = 0; f < 5; f++)
        x[f] = loadF(h, i * 5 + f, isf32) * s_sc[f] + s_sb[f];
#pragma unroll
    for (int f = 0; f < 5; f++) xbn[i * 5 + f] = x[f];
#pragma unroll
    for (int j = 0; j < 5; j++) {
        float a = wts[W_C1PB + j];
#pragma unroll
        for (int k = 0; k < 5; k++) a += x[k] * wts[W_C1PW + k * 5 + j];
        xp1[i * 8 + j] = fmaxf(a, 0.f);
    }
}

// ---------------- CSR build, phase A1: bucket histogram ----------------
__global__ void __launch_bounds__(256) bucket_hist(const int* __restrict__ dst,
                                                   int* __restrict__ bucketCnt) {
    __shared__ int hcnt[NB];
    for (int i = threadIdx.x; i < NB; i += 256) hcnt[i] = 0;
    __syncthreads();
    int per = (N_EDGES + gridDim.x - 1) / gridDim.x;
    int s = blockIdx.x * per;
    int e = min(s + per, N_EDGES);
    for (int i = s + threadIdx.x; i < e; i += 256)
        atomicAdd(&hcnt[dst[i] >> BSH], 1);
    __syncthreads();
    for (int i = threadIdx.x; i < NB; i += 256)
        if (hcnt[i]) atomicAdd(&bucketCnt[i], hcnt[i]);
}

// ---------------- phase A2: exclusive scan of 391 bucket counts ----------------
__global__ void __launch_bounds__(512) bucket_scan(const int* __restrict__ bucketCnt,
                                                   int* __restrict__ bucketStart,
                                                   int* __restrict__ bucketCursor) {
    int tid = threadIdx.x, lane = tid & 63, w = tid >> 6;
    int v = (tid < NB) ? bucketCnt[tid] : 0;
    int sc = v;
#pragma unroll
    for (int o = 1; o < 64; o <<= 1) {
        int t = __shfl_up(sc, o, 64);
        if (lane >= o) sc += t;
    }
    __shared__ int ws[8];
    if (lane == 63) ws[w] = sc;
    __syncthreads();
    if (w == 0) {
        int wv = (lane < 8) ? ws[lane] : 0;
        int s2 = wv;
#pragma unroll
        for (int o = 1; o < 8; o <<= 1) {
            int t = __shfl_up(s2, o, 64);
            if (lane >= o) s2 += t;
        }
        if (lane < 8) ws[lane] = s2;
    }
    __syncthreads();
    int woff = w ? ws[w - 1] : 0;
    int ex = woff + sc - v;
    if (tid < NB) {
        bucketStart[tid] = ex;
        bucketCursor[tid] = ex;
    }
    if (tid == 0) bucketStart[NB] = N_EDGES;
}

// ---------------- phase A3: stage edges bucket-contiguously ({dst, packed}) ----------
__global__ void __launch_bounds__(256) bucket_stage(const int* __restrict__ src,
                                                    const int* __restrict__ dst,
                                                    const void* __restrict__ ew,
                                                    const int* __restrict__ flag,
                                                    int* __restrict__ bucketCursor,
                                                    uint2* __restrict__ stage) {
    __shared__ int hcnt[NB], cur[NB];
    int isf32 = *flag;
    for (int i = threadIdx.x; i < NB; i += 256) hcnt[i] = 0;
    __syncthreads();
    int per = (N_EDGES + gridDim.x - 1) / gridDim.x;
    int s = blockIdx.x * per;
    int e = min(s + per, N_EDGES);
    for (int i = s + threadIdx.x; i < e; i += 256)
        atomicAdd(&hcnt[dst[i] >> BSH], 1);
    __syncthreads();
    for (int i = threadIdx.x; i < NB; i += 256)
        cur[i] = hcnt[i] ? atomicAdd(&bucketCursor[i], hcnt[i]) : 0;
    __syncthreads();
    for (int i = s + threadIdx.x; i < e; i += 256) {
        int d = dst[i];
        int slot = atomicAdd(&cur[d >> BSH], 1);
        stage[slot] = make_uint2((unsigned)d, packEdge(src[i], loadF(ew, i, isf32)));
    }
}

// ---------------- phase B: per-bucket -> node-level CSR (start + perm) ----------------
__global__ void __launch_bounds__(256) bucket_place(const uint2* __restrict__ stage,
                                                    const int* __restrict__ bucketStart,
                                                    int* __restrict__ start,
                                                    unsigned* __restrict__ perm) {
    int b = blockIdx.x, tid = threadIdx.x;
    int base = bucketStart[b];
    int cnt = bucketStart[b + 1] - base;
    int n0 = b << BSH;
    int nn = min(256, N_NODES - n0);
    __shared__ int lcnt[256], loff[256], ws[4];
    lcnt[tid] = 0;
    __syncthreads();
    for (int i = tid; i < cnt; i += 256)
        atomicAdd(&lcnt[stage[base + i].x & 255], 1);
    __syncthreads();
    int lane = tid & 63, w = tid >> 6;
    int v = lcnt[tid];
    int sc = v;
#pragma unroll
    for (int o = 1; o < 64; o <<= 1) {
        int t = __shfl_up(sc, o, 64);
        if (lane >= o) sc += t;
    }
    if (lane == 63) ws[w] = sc;
    __syncthreads();
    int woff = 0;
    for (int k = 0; k < w; k++) woff += ws[k];
    loff[tid] = woff + sc - v;
    __syncthreads();
    if (tid < nn) start[n0 + tid] = base + loff[tid];
    if (b == 0 && tid == 0) start[N_NODES] = N_EDGES;
    lcnt[tid] = 0;
    __syncthreads();
    for (int i = tid; i < cnt; i += 256) {
        uint2 sv = stage[base + i];
        int l = sv.x & 255;
        int p = atomicAdd(&lcnt[l], 1);
        perm[base + loff[l] + p] = sv.y;
    }
}

// ---------------- conv1: lane-parallel gather (padded rows) + epilogue + conv2 proj ----
__global__ void __launch_bounds__(256) conv1_fused(const float* __restrict__ xp1,
                                                   const float* __restrict__ xbn,
                                                   const int* __restrict__ start,
                                                   const unsigned* __restrict__ perm,
                                                   const float* __restrict__ wts,
                                                   float* __restrict__ x1,
                                                   bf16* __restrict__ y2) {
    int lane = threadIdx.x & 63;
    int wid = __builtin_amdgcn_readfirstlane((blockIdx.x * blockDim.x + threadIdx.x) >> 6);
    int nw = (gridDim.x * blockDim.x) >> 6;
    float Wlw[5], Wrw[5];
#pragma unroll
    for (int k = 0; k < 5; k++) {
        Wlw[k] = wts[W_C1LW + k * 64 + lane];
        Wrw[k] = wts[W_C1RW + k * 64 + lane];
    }
    float lb = wts[W_C1LB + lane];
    float W1[64], W2[64];
#pragma unroll
    for (int k = 0; k < 64; k++) W1[k] = wts[W_C2PW + k * 64 + lane];
#pragma unroll
    for (int k = 0; k < 64; k++) W2[k] = wts[W_C2LW + k * 64 + lane];
    float pb = wts[W_C2PB + lane];
    for (int node = wid; node < N_NODES; node += nw) {
        int e0 = start[node], e1 = start[node + 1];
        float s0 = 0, s1 = 0, s2 = 0, s3 = 0, s4 = 0;
        for (int eb = e0; eb < e1; eb += 64) {
            int e = eb + lane;
            if (e < e1) {
                unsigned p = perm[e];
                float w = edgeW(p);
                const float* row = xp1 + (size_t)edgeSrc(p) * 8;
                float4 v4 = *(const float4*)row;
                float v5 = row[4];
                s0 += v4.x * w; s1 += v4.y * w; s2 += v4.z * w;
                s3 += v4.w * w; s4 += v5 * w;
            }
        }
#pragma unroll
        for (int o = 32; o; o >>= 1) {
            s0 += __shfl_xor(s0, o, 64);
            s1 += __shfl_xor(s1, o, 64);
            s2 += __shfl_xor(s2, o, 64);
            s3 += __shfl_xor(s3, o, 64);
            s4 += __shfl_xor(s4, o, 64);
        }
        float ic = 1.f / fmaxf((float)(e1 - e0), 1.f);
        float xb = (lane < 5) ? xbn[node * 5 + lane] : 0.f;
        float out = lb + s0 * ic * Wlw[0] + s1 * ic * Wlw[1] + s2 * ic * Wlw[2] +
                    s3 * ic * Wlw[3] + s4 * ic * Wlw[4];
#pragma unroll
        for (int k = 0; k < 5; k++) out += RL(xb, k) * Wrw[k];
        float ss = out * out;
#pragma unroll
        for (int o = 32; o; o >>= 1) ss += __shfl_xor(ss, o, 64);
        float xv = fmaxf(out / fmaxf(sqrtf(ss), 1e-12f), 0.f);
        x1[(size_t)node * 64 + lane] = xv;
        float a0 = pb, a1 = 0.f, a2 = 0.f, a3 = 0.f;
#pragma unroll
        for (int k = 0; k < 64; k += 4) {
            a0 += RL(xv, k) * W1[k];
            a1 += RL(xv, k + 1) * W1[k + 1];
            a2 += RL(xv, k + 2) * W1[k + 2];
            a3 += RL(xv, k + 3) * W1[k + 3];
        }
        float xp = fmaxf((a0 + a1) + (a2 + a3), 0.f);
        float b0 = 0.f, b1 = 0.f, b2 = 0.f, b3 = 0.f;
#pragma unroll
        for (int k = 0; k < 64; k += 4) {
            b0 += RL(xp, k) * W2[k];
            b1 += RL(xp, k + 1) * W2[k + 1];
            b2 += RL(xp, k + 2) * W2[k + 2];
            b3 += RL(xp, k + 3) * W2[k + 3];
        }
        y2[(size_t)node * 64 + lane] = __float2bfloat16((b0 + b1) + (b2 + b3));
    }
}

// ---------------- conv2: gather(bf16, 16-deep pipelined) + root + L2norm (56 VGPR) ------
// NOTE: do NOT fuse more weight matrices in here — latency-bound, lives on occupancy
// (round 10: +W3[64] => VGPR 84, occ 30%, 199us vs 113us).
__global__ void __launch_bounds__(256) conv2_fused_reg(const bf16* __restrict__ y2,
                                                       const int* __restrict__ start,
                                                       const unsigned* __restrict__ perm,
                                                       const float* __restrict__ x1,
                                                       const float* __restrict__ wts,
                                                       float* __restrict__ x2) {
    int lane = threadIdx.x & 63;
    int wid = __builtin_amdgcn_readfirstlane((blockIdx.x * blockDim.x + threadIdx.x) >> 6);
    int nw = (gridDim.x * blockDim.x) >> 6;
    float W[64];
#pragma unroll
    for (int k = 0; k < 64; k++) W[k] = wts[W_C2RW + k * 64 + lane];
    float lb = wts[W_C2LB + lane];
    for (int node = wid; node < N_NODES; node += nw) {
        int e0 = start[node], e1 = start[node + 1];
        float acc = 0.f;
        int e = e0;
        for (; e + 16 <= e1; e += 16) {
            unsigned p[16];
#pragma unroll
            for (int u = 0; u < 16; u++) p[u] = perm[e + u];
            float v[16];
#pragma unroll
            for (int u = 0; u < 16; u++)
                v[u] = __bfloat162float(y2[(size_t)edgeSrc(p[u]) * 64 + lane]);
#pragma unroll
            for (int u = 0; u < 16; u++) acc += v[u] * edgeW(p[u]);
        }
        for (; e + 4 <= e1; e += 4) {
            unsigned p[4];
#pragma unroll
            for (int u = 0; u < 4; u++) p[u] = perm[e + u];
            float v[4];
#pragma unroll
            for (int u = 0; u < 4; u++)
                v[u] = __bfloat162float(y2[(size_t)edgeSrc(p[u]) * 64 + lane]);
#pragma unroll
            for (int u = 0; u < 4; u++) acc += v[u] * edgeW(p[u]);
        }
        for (; e < e1; e++) {
            unsigned p = perm[e];
            acc += __bfloat162float(y2[(size_t)edgeSrc(p) * 64 + lane]) * edgeW(p);
        }
        float ic = 1.f / fmaxf((float)(e1 - e0), 1.f);
        float xv = x1[(size_t)node * 64 + lane];
        float o0 = acc * ic + lb, o1 = 0.f, o2 = 0.f, o3 = 0.f;
#pragma unroll
        for (int k = 0; k < 64; k += 4) {
            o0 += RL(xv, k) * W[k];
            o1 += RL(xv, k + 1) * W[k + 1];
            o2 += RL(xv, k + 2) * W[k + 2];
            o3 += RL(xv, k + 3) * W[k + 3];
        }
        float out = (o0 + o1) + (o2 + o3);
        float ss = out * out;
#pragma unroll
        for (int o = 32; o; o >>= 1) ss += __shfl_xor(ss, o, 64);
        float v = out / fmaxf(sqrtf(ss), 1e-12f);
        x2[(size_t)node * 64 + lane] = fmaxf(v, 0.f);
    }
}

// ---------------- conv3 projection, W-in-VGPR: y3 = relu(x2@pw3+pb3)@lw3 (64->5, pad 8) --
__global__ void __launch_bounds__(256) proj3_reg(const float* __restrict__ x2,
                                                 const float* __restrict__ wts,
                                                 float* __restrict__ y3) {
    int lane = threadIdx.x & 63;
    int wid = __builtin_amdgcn_readfirstlane((blockIdx.x * blockDim.x + threadIdx.x) >> 6);
    int nw = (gridDim.x * blockDim.x) >> 6;
    float W1[64], Wl[5];
#pragma unroll
    for (int k = 0; k < 64; k++) W1[k] = wts[W_C3PW + k * 64 + lane];
#pragma unroll
    for (int j = 0; j < 5; j++) Wl[j] = wts[W_C3LW + lane * 5 + j];
    float pb = wts[W_C3PB + lane];
    for (int node = wid; node < N_NODES; node += nw) {
        float xv = x2[(size_t)node * 64 + lane];
        float a0 = pb, a1 = 0.f, a2 = 0.f, a3 = 0.f;
#pragma unroll
        for (int k = 0; k < 64; k += 4) {
            a0 += RL(xv, k) * W1[k];
            a1 += RL(xv, k + 1) * W1[k + 1];
            a2 += RL(xv, k + 2) * W1[k + 2];
            a3 += RL(xv, k + 3) * W1[k + 3];
        }
        float xp = fmaxf((a0 + a1) + (a2 + a3), 0.f);
#pragma unroll
        for (int j = 0; j < 5; j++) {
            float p = xp * Wl[j];
#pragma unroll
            for (int o = 32; o; o >>= 1) p += __shfl_xor(p, o, 64);
            if (lane == j) y3[(size_t)node * 8 + j] = p;
        }
    }
}

// ---------------- conv3: lane-parallel gather (padded rows) + epilogue (no relu) -------
__global__ void __launch_bounds__(256) conv3_fused(const float* __restrict__ y3,
                                                   const float* __restrict__ x2,
                                                   const int* __restrict__ start,
                                                   const unsigned* __restrict__ perm,
                                                   const float* __restrict__ wts,
                                                   const int* __restrict__ flag,
                                                   void* __restrict__ outp) {
    int lane = threadIdx.x & 63;
    int wid = __builtin_amdgcn_readfirstlane((blockIdx.x * blockDim.x + threadIdx.x) >> 6);
    int nw = (gridDim.x * blockDim.x) >> 6;
    float Wr[5];
#pragma unroll
    for (int j = 0; j < 5; j++) Wr[j] = wts[W_C3RW + lane * 5 + j];
    float lb3[5];
#pragma unroll
    for (int j = 0; j < 5; j++) lb3[j] = wts[W_C3LB + j];
    int isf32 = *flag;
    for (int node = wid; node < N_NODES; node += nw) {
        int e0 = start[node], e1 = start[node + 1];
        float s0 = 0, s1 = 0, s2 = 0, s3 = 0, s4 = 0;
        for (int eb = e0; eb < e1; eb += 64) {
            int e = eb + lane;
            if (e < e1) {
                unsigned p = perm[e];
                float w = edgeW(p);
                const float* row = y3 + (size_t)edgeSrc(p) * 8;
                float4 v4 = *(const float4*)row;
                float v5 = row[4];
                s0 += v4.x * w; s1 += v4.y * w; s2 += v4.z * w;
                s3 += v4.w * w; s4 += v5 * w;
            }
        }
#pragma unroll
        for (int o = 32; o; o >>= 1) {
            s0 += __shfl_xor(s0, o, 64);
            s1 += __shfl_xor(s1, o, 64);
            s2 += __shfl_xor(s2, o, 64);
            s3 += __shfl_xor(s3, o, 64);
            s4 += __shfl_xor(s4, o, 64);
        }
        float ic = 1.f / fmaxf((float)(e1 - e0), 1.f);
        float xv = x2[(size_t)node * 64 + lane];
        float m[5] = {s0 * ic, s1 * ic, s2 * ic, s3 * ic, s4 * ic};
        float r[5], ss = 0.f;
#pragma unroll
        for (int j = 0; j < 5; j++) {
            float p = xv * Wr[j];
#pragma unroll
            for (int o = 32; o; o >>= 1) p += __shfl_xor(p, o, 64);
            r[j] = p + m[j] + lb3[j];
            ss += r[j] * r[j];
        }
        float inv = 1.f / fmaxf(sqrtf(ss), 1e-12f);
#pragma unroll
        for (int j = 0; j < 5; j++) {
            if (lane == j) {
                float v = r[j] * inv;
                if (isf32) ((float*)outp)[node * 5 + j] = v;
                else ((bf16*)outp)[node * 5 + j] = __float2bfloat16(v);
            }
        }
    }
}

extern "C" void kernel_launch(void* const* d_in, const int* in_sizes, int n_in,
                              void* d_out, int out_size, void* d_ws, size_t ws_size,
                              hipStream_t stream) {
    const void* h = d_in[0];
    const int* ei = (const int*)d_in[1];
    const int* src = ei;
    const int* dst = ei + N_EDGES;
    const void* ew = d_in[2];

    float* W = (float*)d_ws;
    int* flag = (int*)W;                            // [0]
    float* stats = W + 16;                          // 32 floats
    float* wts = W + 64;                            // ~18k floats
    float* xbn = W + 20480;                         // N*5
    float* xp1 = xbn + N_NODES * 5;                 // N*8 padded (aliased by y3 later)
    int* startp = (int*)(xp1 + N_NODES * 8);        // N+1 ints (+pad)
    int* bucketCnt = startp + N_NODES + 64;         // NB ints
    int* bucketStart = bucketCnt + NB + 1;          // NB+1 ints
    int* bucketCursor = bucketStart + NB + 1;       // NB ints
    unsigned* perm = (unsigned*)(bucketCursor + NB + 62); // E u32 (packed src|w)
    float* x1 = (float*)(perm + N_EDGES);           // N*64 f32
    uint2* stage = (uint2*)x1;                      // E uint2 (dead before x1 written)
    bf16* y2 = (bf16*)(x1 + (size_t)N_NODES * 64);  // N*64 bf16
    float* x2 = x1;                                 // alias: per-thread same-idx read->write
    float* y3 = xp1;                                // alias: xp1 dead after conv1_fused

    detect_dtype<<<1, 64, 0, stream>>>(ew, flag);
    cvt_weights<<<17, 256, 0, stream>>>(flag,
        d_in[3], d_in[4],
        d_in[5], d_in[6], d_in[7], d_in[8], d_in[9],
        d_in[10], d_in[11], d_in[12], d_in[13], d_in[14],
        d_in[15], d_in[16], d_in[17], d_in[18], d_in[19],
        wts);

    hipMemsetAsync(stats, 0, 32 * sizeof(float), stream);
    hipMemsetAsync(bucketCnt, 0, NB * sizeof(int), stream);

    bn_stats<<<200, 256, 0, stream>>>(h, flag, stats);
    bn_proj1<<<(N_NODES + 255) / 256, 256, 0, stream>>>(h, flag, stats, wts, xbn, xp1);

    // CSR build: bucketed two-phase (no global random-write-through)
    bucket_hist<<<512, 256, 0, stream>>>(dst, bucketCnt);
    bucket_scan<<<1, 512, 0, stream>>>(bucketCnt, bucketStart, bucketCursor);
    bucket_stage<<<512, 256, 0, stream>>>(src, dst, ew, flag, bucketCursor, stage);
    bucket_place<<<NB, 256, 0, stream>>>(stage, bucketStart, startp, perm);

    // conv1: gather + epilogue + conv2-projection
    conv1_fused<<<2048, 256, 0, stream>>>(xp1, xbn, startp, perm, wts, x1, y2);

    // conv2 (latency-bound gather — keep lean)
    conv2_fused_reg<<<4096, 256, 0, stream>>>(y2, startp, perm, x1, wts, x2);

    // conv3: projection then gather + epilogue
    proj3_reg<<<2048, 256, 0, stream>>>(x2, wts, y3);
    conv3_fused<<<2048, 256, 0, stream>>>(y3, x2, startp, perm, wts, flag, d_out);
}